// Round 1
// baseline (631.312 us; speedup 1.0000x reference)
//
#include <hip/hip_runtime.h>
#include <hip/hip_bf16.h>

typedef float  f32x4  __attribute__((ext_vector_type(4)));
typedef short  bf16x8 __attribute__((ext_vector_type(8)));
typedef short  bf16x4 __attribute__((ext_vector_type(4)));

namespace {

constexpr int B_ = 2;
constexpr int S_ = 1024;
constexpr int H_ = 1024;
constexpr int V_ = 50257;
constexpr int M_ = B_ * S_;          // 2048
constexpr float DT_ = 0.1f;
constexpr float THRESH_ = 10.0f;

constexpr int BM = 128, BN = 128, BK = 32;
constexpr int LDT = BK + 8;          // padded bf16 LDS stride = 40 (80 B) breaks b128 bank conflicts

__device__ __forceinline__ unsigned short f2bf(float f) {
  union { float f; unsigned u; } x;
  x.f = f;
  x.u += 0x7FFFu + ((x.u >> 16) & 1u);   // RNE (no NaNs in this problem)
  return (unsigned short)(x.u >> 16);
}

// ---------------- Kernel 1: impulses[s*B+b] = hidden[m,:] . W_imp[0,:] + b_imp[0]
__global__ void ttu_impulse_kernel(const float* __restrict__ hidden,
                                   const float* __restrict__ W_imp,
                                   const float* __restrict__ b_imp,
                                   float* __restrict__ imp) {
  const int m = blockIdx.x;            // m = b*S + s
  const int t = threadIdx.x;           // 256 threads, 4 floats each
  const float4 hv = reinterpret_cast<const float4*>(hidden + (size_t)m * H_)[t];
  const float4 wv = reinterpret_cast<const float4*>(W_imp)[t];  // row 0 of W_imp
  float p = hv.x * wv.x + hv.y * wv.y + hv.z * wv.z + hv.w * wv.w;
  #pragma unroll
  for (int off = 32; off; off >>= 1) p += __shfl_down(p, off);
  __shared__ float partial[4];
  if ((t & 63) == 0) partial[t >> 6] = p;
  __syncthreads();
  if (t == 0) {
    const float v = partial[0] + partial[1] + partial[2] + partial[3] + b_imp[0];
    const int b = m >> 10;
    const int s = m & (S_ - 1);
    imp[s * B_ + b] = v;
  }
}

// ---------------- Kernel 2: serial nonlinear scan (S steps, B=2 lanes active)
__global__ void ttu_scan_kernel(const float* __restrict__ imp,
                                const float* __restrict__ ttu_state,
                                const float* __restrict__ ttu_params,
                                float* __restrict__ states,     // (S,B,3) in ws
                                float* __restrict__ final_out) { // d_out + B*S*V
  __shared__ float imp_s[S_ * B_];
  const int t = threadIdx.x;  // 64
  for (int i = t; i < S_ * B_; i += 64) imp_s[i] = imp[i];
  __syncthreads();
  if (t < B_) {
    const float gamma   = ttu_params[0];
    const float alpha_c = ttu_params[1];
    const float beta_c  = ttu_params[2];
    const float delta   = ttu_params[3];
    const float alpha_d = ttu_params[4];
    const float epsilon = ttu_params[5];
    const float alpha_m = ttu_params[6];
    float c = ttu_state[t * 3 + 0];
    float d = ttu_state[t * 3 + 1];
    float m = ttu_state[t * 3 + 2];
    for (int s = 0; s < S_; ++s) {
      const float ii = imp_s[s * B_ + t];
      const float dc = gamma * ii - alpha_c * c - beta_c * c * d;
      const float dd = delta * c * c - alpha_d * d;
      const float dm = epsilon * d - alpha_m * m;
      c = c + DT_ * dc;
      float nd = d + DT_ * dd;
      m = m + DT_ * dm;
      nd = (fabsf(nd) > THRESH_ ? 0.5f : 1.0f) * nd;
      d = nd;
      float* st = states + (size_t)(s * B_ + t) * 3;
      st[0] = c; st[1] = d; st[2] = m;
    }
    final_out[t * 3 + 0] = c;
    final_out[t * 3 + 1] = d;
    final_out[t * 3 + 2] = m;
  }
}

// ---------------- Kernel 3: logits = hidden . W_lm^T + 0.1 * states . W_mod^T (fused epilogue)
__global__ __launch_bounds__(256) void ttu_gemm_kernel(
    const float* __restrict__ Ag,      // hidden (M,K) f32
    const float* __restrict__ Bg,      // W_lm (V,K) f32
    const float* __restrict__ states,  // (S,B,3) f32
    const float* __restrict__ Wmod,    // (V,3) f32
    float* __restrict__ out)           // (M,V) f32
{
  __shared__ unsigned short A_s[BM][LDT];
  __shared__ unsigned short B_s[BN][LDT];
  __shared__ float st_s[BM][3];
  __shared__ float wm_s[BN][3];

  const int t   = threadIdx.x;
  const int bid = blockIdx.x;
  const int mb  = bid & 15;            // 16 M-blocks
  const int nb  = bid >> 4;            // 393 N-blocks
  const int m0  = mb * BM;
  const int n0  = nb * BN;

  // Stage epilogue operands (states per row, W_mod per column)
  if (t < BM) {
    const int m = m0 + t;
    const int b = m >> 10;
    const int s = m & (S_ - 1);
    const float* st = states + (size_t)(s * B_ + b) * 3;
    st_s[t][0] = st[0]; st_s[t][1] = st[1]; st_s[t][2] = st[2];
  } else {
    const int tt = t - BM;
    const int n  = n0 + tt;
    const bool ok = n < V_;
    wm_s[tt][0] = ok ? Wmod[n * 3 + 0] : 0.f;
    wm_s[tt][1] = ok ? Wmod[n * 3 + 1] : 0.f;
    wm_s[tt][2] = ok ? Wmod[n * 3 + 2] : 0.f;
  }

  // Staging assignment: thread -> (row r, 16-float segment seg)
  const int r   = t >> 1;
  const int seg = t & 1;
  const float* arow = Ag + (size_t)(m0 + r) * H_ + seg * 16;
  const int  vrow = n0 + r;
  const bool bok  = vrow < V_;
  const float* brow = Bg + (size_t)(bok ? vrow : 0) * H_ + seg * 16;

  // Wave/fragment geometry (2x2 waves, each 64x64 = 4x4 fragments of 16x16)
  const int lane = t & 63;
  const int wid  = t >> 6;
  const int wm   = wid >> 1;
  const int wn   = wid & 1;
  const int lm   = lane & 15;
  const int kg   = lane >> 4;          // k-group 0..3

  f32x4 acc[4][4];
  #pragma unroll
  for (int i = 0; i < 4; ++i)
    #pragma unroll
    for (int j = 0; j < 4; ++j)
      acc[i][j] = (f32x4){0.f, 0.f, 0.f, 0.f};

  for (int kt = 0; kt < H_ / BK; ++kt) {
    const int k0 = kt * BK;
    // global loads (f32)
    const float4 av0 = *(const float4*)(arow + k0 + 0);
    const float4 av1 = *(const float4*)(arow + k0 + 4);
    const float4 av2 = *(const float4*)(arow + k0 + 8);
    const float4 av3 = *(const float4*)(arow + k0 + 12);
    float4 bv0 = {0,0,0,0}, bv1 = {0,0,0,0}, bv2 = {0,0,0,0}, bv3 = {0,0,0,0};
    if (bok) {
      bv0 = *(const float4*)(brow + k0 + 0);
      bv1 = *(const float4*)(brow + k0 + 4);
      bv2 = *(const float4*)(brow + k0 + 8);
      bv3 = *(const float4*)(brow + k0 + 12);
    }
    __syncthreads();   // previous iter's ds_reads done
    // convert + LDS write (4 bf16 per 8B ds_write)
    #define CVT4(v) (bf16x4){(short)f2bf((v).x), (short)f2bf((v).y), (short)f2bf((v).z), (short)f2bf((v).w)}
    *(bf16x4*)&A_s[r][seg * 16 + 0]  = CVT4(av0);
    *(bf16x4*)&A_s[r][seg * 16 + 4]  = CVT4(av1);
    *(bf16x4*)&A_s[r][seg * 16 + 8]  = CVT4(av2);
    *(bf16x4*)&A_s[r][seg * 16 + 12] = CVT4(av3);
    *(bf16x4*)&B_s[r][seg * 16 + 0]  = CVT4(bv0);
    *(bf16x4*)&B_s[r][seg * 16 + 4]  = CVT4(bv1);
    *(bf16x4*)&B_s[r][seg * 16 + 8]  = CVT4(bv2);
    *(bf16x4*)&B_s[r][seg * 16 + 12] = CVT4(bv3);
    #undef CVT4
    __syncthreads();   // tile ready
    // fragments + MFMA
    bf16x8 af[4], bf[4];
    #pragma unroll
    for (int i = 0; i < 4; ++i) {
      af[i] = *(const bf16x8*)&A_s[wm * 64 + i * 16 + lm][kg * 8];
      bf[i] = *(const bf16x8*)&B_s[wn * 64 + i * 16 + lm][kg * 8];
    }
    #pragma unroll
    for (int i = 0; i < 4; ++i)
      #pragma unroll
      for (int j = 0; j < 4; ++j)
        acc[i][j] = __builtin_amdgcn_mfma_f32_16x16x32_bf16(af[i], bf[j], acc[i][j], 0, 0, 0);
  }

  // Epilogue: += 0.1 * states . W_mod^T, store f32
  #pragma unroll
  for (int j = 0; j < 4; ++j) {
    const int nloc = wn * 64 + j * 16 + lm;
    const int n = n0 + nloc;
    if (n < V_) {
      const float w0 = wm_s[nloc][0], w1 = wm_s[nloc][1], w2 = wm_s[nloc][2];
      #pragma unroll
      for (int i = 0; i < 4; ++i) {
        #pragma unroll
        for (int rr = 0; rr < 4; ++rr) {
          const int mloc = wm * 64 + i * 16 + kg * 4 + rr;
          const float corr = 0.1f * (st_s[mloc][0] * w0 + st_s[mloc][1] * w1 + st_s[mloc][2] * w2);
          out[(size_t)(m0 + mloc) * V_ + n] = acc[i][j][rr] + corr;
        }
      }
    }
  }
}

} // namespace

extern "C" void kernel_launch(void* const* d_in, const int* in_sizes, int n_in,
                              void* d_out, int out_size, void* d_ws, size_t ws_size,
                              hipStream_t stream) {
  const float* hidden     = (const float*)d_in[0];
  const float* ttu_state  = (const float*)d_in[1];
  const float* W_imp      = (const float*)d_in[2];
  const float* b_imp      = (const float*)d_in[3];
  const float* W_lm       = (const float*)d_in[4];
  const float* W_mod      = (const float*)d_in[5];
  const float* ttu_params = (const float*)d_in[6];
  float* out = (float*)d_out;

  float* imp    = (float*)d_ws;          // S*B floats
  float* states = imp + S_ * B_;         // S*B*3 floats (32 KB total ws use)

  ttu_impulse_kernel<<<M_, 256, 0, stream>>>(hidden, W_imp, b_imp, imp);
  ttu_scan_kernel<<<1, 64, 0, stream>>>(imp, ttu_state, ttu_params, states,
                                        out + (size_t)B_ * S_ * V_);
  const int grid = ((V_ + BN - 1) / BN) * (M_ / BM);   // 393 * 16 = 6288
  ttu_gemm_kernel<<<grid, 256, 0, stream>>>(hidden, W_lm, states, W_mod, out);
}

// Round 2
// 588.952 us; speedup vs baseline: 1.0719x; 1.0719x over previous
//
#include <hip/hip_runtime.h>
#include <hip/hip_bf16.h>

typedef float  f32x4  __attribute__((ext_vector_type(4)));
typedef short  bf16x8 __attribute__((ext_vector_type(8)));
typedef short  bf16x4 __attribute__((ext_vector_type(4)));

typedef const void __attribute__((address_space(1))) gv_t;
typedef void __attribute__((address_space(3))) sv_t;

namespace {

constexpr int B_ = 2;
constexpr int S_ = 1024;
constexpr int H_ = 1024;
constexpr int V_ = 50257;
constexpr int M_ = B_ * S_;          // 2048
constexpr int VP_ = 50304;           // 393*128, zero-padded W_lm rows
constexpr float DT_ = 0.1f;
constexpr float THRESH_ = 10.0f;

constexpr int BM = 128, BN = 128, BK = 64;
constexpr int LDT = 40;              // fallback path pad

__device__ __forceinline__ unsigned short f2bf(float f) {
  union { float f; unsigned u; } x;
  x.f = f;
  x.u += 0x7FFFu + ((x.u >> 16) & 1u);   // RNE (no NaNs in this problem)
  return (unsigned short)(x.u >> 16);
}

// ---------------- Kernel 1: impulses[s*B+b] = hidden[m,:] . W_imp[0,:] + b_imp[0]
__global__ void ttu_impulse_kernel(const float* __restrict__ hidden,
                                   const float* __restrict__ W_imp,
                                   const float* __restrict__ b_imp,
                                   float* __restrict__ imp) {
  const int m = blockIdx.x;
  const int t = threadIdx.x;           // 256 threads, 4 floats each
  const float4 hv = reinterpret_cast<const float4*>(hidden + (size_t)m * H_)[t];
  const float4 wv = reinterpret_cast<const float4*>(W_imp)[t];
  float p = hv.x * wv.x + hv.y * wv.y + hv.z * wv.z + hv.w * wv.w;
  #pragma unroll
  for (int off = 32; off; off >>= 1) p += __shfl_down(p, off);
  __shared__ float partial[4];
  if ((t & 63) == 0) partial[t >> 6] = p;
  __syncthreads();
  if (t == 0) {
    const float v = partial[0] + partial[1] + partial[2] + partial[3] + b_imp[0];
    const int b = m >> 10;
    const int s = m & (S_ - 1);
    imp[s * B_ + b] = v;
  }
}

// ---------------- Kernel 2: serial nonlinear scan
__global__ void ttu_scan_kernel(const float* __restrict__ imp,
                                const float* __restrict__ ttu_state,
                                const float* __restrict__ ttu_params,
                                float* __restrict__ states,
                                float* __restrict__ final_out) {
  __shared__ float imp_s[S_ * B_];
  const int t = threadIdx.x;  // 64
  for (int i = t; i < S_ * B_; i += 64) imp_s[i] = imp[i];
  __syncthreads();
  if (t < B_) {
    const float gamma   = ttu_params[0];
    const float alpha_c = ttu_params[1];
    const float beta_c  = ttu_params[2];
    const float delta   = ttu_params[3];
    const float alpha_d = ttu_params[4];
    const float epsilon = ttu_params[5];
    const float alpha_m = ttu_params[6];
    float c = ttu_state[t * 3 + 0];
    float d = ttu_state[t * 3 + 1];
    float m = ttu_state[t * 3 + 2];
    for (int s = 0; s < S_; ++s) {
      const float ii = imp_s[s * B_ + t];
      const float dc = gamma * ii - alpha_c * c - beta_c * c * d;
      const float dd = delta * c * c - alpha_d * d;
      const float dm = epsilon * d - alpha_m * m;
      c = c + DT_ * dc;
      float nd = d + DT_ * dd;
      m = m + DT_ * dm;
      nd = (fabsf(nd) > THRESH_ ? 0.5f : 1.0f) * nd;
      d = nd;
      float* st = states + (size_t)(s * B_ + t) * 3;
      st[0] = c; st[1] = d; st[2] = m;
    }
    final_out[t * 3 + 0] = c;
    final_out[t * 3 + 1] = d;
    final_out[t * 3 + 2] = m;
  }
}

// ---------------- Kernel 2.5: f32 -> bf16 convert (zero-fill past n_src)
__global__ void cvt_bf16_kernel(const float* __restrict__ src,
                                unsigned short* __restrict__ dst,
                                long n_src, long n_dst) {
  const long stride = (long)gridDim.x * blockDim.x * 8;
  for (long i = ((long)blockIdx.x * blockDim.x + threadIdx.x) * 8; i < n_dst; i += stride) {
    bf16x8 v;
    if (i < n_src) {     // n_src is a multiple of 8; vectors never straddle
      const float4 a = *(const float4*)(src + i);
      const float4 b = *(const float4*)(src + i + 4);
      v[0] = (short)f2bf(a.x); v[1] = (short)f2bf(a.y);
      v[2] = (short)f2bf(a.z); v[3] = (short)f2bf(a.w);
      v[4] = (short)f2bf(b.x); v[5] = (short)f2bf(b.y);
      v[6] = (short)f2bf(b.z); v[7] = (short)f2bf(b.w);
    } else {
      v = (bf16x8){0, 0, 0, 0, 0, 0, 0, 0};
    }
    *(bf16x8*)(dst + i) = v;
  }
}

// ---------------- Kernel 3 (fast): bf16 GEMM, global_load_lds + XOR swizzle
// LDS[row][chunk c] (c = 16B unit, 8 bf16) holds global chunk c ^ (row&7):
// stage pre-swizzles the per-lane GLOBAL address (linear LDS dest, rule #21),
// ds_read applies the same XOR.
__global__ __launch_bounds__(256) void ttu_gemm_bf16_kernel(
    const unsigned short* __restrict__ Ab,   // hidden bf16 [M_][H_]
    const unsigned short* __restrict__ Bb,   // W_lm bf16 [VP_][H_] (zero-padded)
    const float* __restrict__ states,
    const float* __restrict__ Wmod,
    float* __restrict__ out)
{
  __shared__ unsigned short A_s[BM * BK];
  __shared__ unsigned short B_s[BN * BK];
  __shared__ float st_s[BM][3];
  __shared__ float wm_s[BN][3];

  const int t = threadIdx.x;
  // T1: XCD-chunked swizzle; grid = 6288, 6288 % 8 == 0 -> simple form bijective
  const int cpx = gridDim.x >> 3;
  const int bid = (blockIdx.x & 7) * cpx + (blockIdx.x >> 3);
  const int mb = bid & 15;             // M fastest: 16 consecutive blocks share B-panel
  const int nb = bid >> 4;
  const int m0 = mb * BM;
  const int n0 = nb * BN;

  // epilogue operands
  if (t < BM) {
    const int m = m0 + t;
    const int b = m >> 10;
    const int s = m & (S_ - 1);
    const float* st = states + (size_t)(s * B_ + b) * 3;
    st_s[t][0] = st[0]; st_s[t][1] = st[1]; st_s[t][2] = st[2];
  } else {
    const int tt = t - BM;
    const int n = n0 + tt;
    const bool ok = n < V_;
    wm_s[tt][0] = ok ? Wmod[n * 3 + 0] : 0.f;
    wm_s[tt][1] = ok ? Wmod[n * 3 + 1] : 0.f;
    wm_s[tt][2] = ok ? Wmod[n * 3 + 2] : 0.f;
  }

  const int lane = t & 63;
  const int wid  = t >> 6;             // 4 waves
  const int lr   = lane >> 3;          // staging: sub-row 0..7
  const int ch   = lane & 7;           // staging: 16B chunk 0..7
  const int wm   = wid >> 1;           // 2x2 wave grid
  const int wn   = wid & 1;
  const int lm   = lane & 15;
  const int kg   = lane >> 4;

  f32x4 acc[4][4];
  #pragma unroll
  for (int i = 0; i < 4; ++i)
    #pragma unroll
    for (int j = 0; j < 4; ++j)
      acc[i][j] = (f32x4){0.f, 0.f, 0.f, 0.f};

  const unsigned short* Abase = Ab + (size_t)m0 * H_;
  const unsigned short* Bbase = Bb + (size_t)n0 * H_;

  for (int kt = 0; kt < H_ / BK; ++kt) {
    const int k0 = kt * BK;
    // stage A and B tiles: 4 instrs per wave per matrix, 8 rows (8x128B) each
    #pragma unroll
    for (int ins = 0; ins < 4; ++ins) {
      const int lrow = wid * 32 + ins * 8 + lr;
      const int sch  = ch ^ (lrow & 7);                    // pre-swizzled source chunk
      __builtin_amdgcn_global_load_lds(
          (gv_t*)(Abase + (size_t)lrow * H_ + k0 + sch * 8),
          (sv_t*)(A_s + (wid * 32 + ins * 8) * BK), 16, 0, 0);
    }
    #pragma unroll
    for (int ins = 0; ins < 4; ++ins) {
      const int lrow = wid * 32 + ins * 8 + lr;
      const int sch  = ch ^ (lrow & 7);
      __builtin_amdgcn_global_load_lds(
          (gv_t*)(Bbase + (size_t)lrow * H_ + k0 + sch * 8),
          (sv_t*)(B_s + (wid * 32 + ins * 8) * BK), 16, 0, 0);
    }
    __syncthreads();   // drains vmcnt(0): tile visible

    bf16x8 af[4][2], bfr[4][2];
    #pragma unroll
    for (int i = 0; i < 4; ++i) {
      const int arow = wm * 64 + i * 16 + lm;
      const int brow = wn * 64 + i * 16 + lm;
      #pragma unroll
      for (int ks = 0; ks < 2; ++ks) {
        af[i][ks]  = *(const bf16x8*)&A_s[arow * BK + (((ks * 4 + kg) ^ (arow & 7)) << 3)];
        bfr[i][ks] = *(const bf16x8*)&B_s[brow * BK + (((ks * 4 + kg) ^ (brow & 7)) << 3)];
      }
    }
    #pragma unroll
    for (int ks = 0; ks < 2; ++ks)
      #pragma unroll
      for (int i = 0; i < 4; ++i)
        #pragma unroll
        for (int j = 0; j < 4; ++j)
          acc[i][j] = __builtin_amdgcn_mfma_f32_16x16x32_bf16(af[i][ks], bfr[j][ks], acc[i][j], 0, 0, 0);
    __syncthreads();   // all reads done before next stage overwrites
  }

  // Epilogue: += 0.1 * states . W_mod^T; row-major store order for line merging
  #pragma unroll
  for (int i = 0; i < 4; ++i) {
    #pragma unroll
    for (int rr = 0; rr < 4; ++rr) {
      const int mloc = wm * 64 + i * 16 + kg * 4 + rr;
      const float s0 = st_s[mloc][0], s1 = st_s[mloc][1], s2 = st_s[mloc][2];
      float* orow = out + (size_t)(m0 + mloc) * V_ + n0;
      #pragma unroll
      for (int j = 0; j < 4; ++j) {
        const int nloc = wn * 64 + j * 16 + lm;
        if (n0 + nloc < V_) {
          const float corr = 0.1f * (s0 * wm_s[nloc][0] + s1 * wm_s[nloc][1] + s2 * wm_s[nloc][2]);
          orow[nloc] = acc[i][j][rr] + corr;
        }
      }
    }
  }
}

// ---------------- Kernel 3 (fallback, R1): f32 reg-staged GEMM
__global__ __launch_bounds__(256) void ttu_gemm_kernel(
    const float* __restrict__ Ag, const float* __restrict__ Bg,
    const float* __restrict__ states, const float* __restrict__ Wmod,
    float* __restrict__ out)
{
  __shared__ unsigned short A_s[BM][LDT];
  __shared__ unsigned short B_s[BM][LDT];
  __shared__ float st_s[BM][3];
  __shared__ float wm_s[BM][3];

  const int t   = threadIdx.x;
  const int bid = blockIdx.x;
  const int mb  = bid & 15;
  const int nb  = bid >> 4;
  const int m0  = mb * BM;
  const int n0  = nb * BM;

  if (t < BM) {
    const int m = m0 + t;
    const int b = m >> 10;
    const int s = m & (S_ - 1);
    const float* st = states + (size_t)(s * B_ + b) * 3;
    st_s[t][0] = st[0]; st_s[t][1] = st[1]; st_s[t][2] = st[2];
  } else {
    const int tt = t - BM;
    const int n  = n0 + tt;
    const bool ok = n < V_;
    wm_s[tt][0] = ok ? Wmod[n * 3 + 0] : 0.f;
    wm_s[tt][1] = ok ? Wmod[n * 3 + 1] : 0.f;
    wm_s[tt][2] = ok ? Wmod[n * 3 + 2] : 0.f;
  }

  const int r   = t >> 1;
  const int seg = t & 1;
  const float* arow = Ag + (size_t)(m0 + r) * H_ + seg * 16;
  const int  vrow = n0 + r;
  const bool bok  = vrow < V_;
  const float* brow = Bg + (size_t)(bok ? vrow : 0) * H_ + seg * 16;

  const int lane = t & 63;
  const int wid  = t >> 6;
  const int wm   = wid >> 1;
  const int wn   = wid & 1;
  const int lm   = lane & 15;
  const int kg   = lane >> 4;

  f32x4 acc[4][4];
  #pragma unroll
  for (int i = 0; i < 4; ++i)
    #pragma unroll
    for (int j = 0; j < 4; ++j)
      acc[i][j] = (f32x4){0.f, 0.f, 0.f, 0.f};

  for (int kt = 0; kt < H_ / 32; ++kt) {
    const int k0 = kt * 32;
    const float4 av0 = *(const float4*)(arow + k0 + 0);
    const float4 av1 = *(const float4*)(arow + k0 + 4);
    const float4 av2 = *(const float4*)(arow + k0 + 8);
    const float4 av3 = *(const float4*)(arow + k0 + 12);
    float4 bv0 = {0,0,0,0}, bv1 = {0,0,0,0}, bv2 = {0,0,0,0}, bv3 = {0,0,0,0};
    if (bok) {
      bv0 = *(const float4*)(brow + k0 + 0);
      bv1 = *(const float4*)(brow + k0 + 4);
      bv2 = *(const float4*)(brow + k0 + 8);
      bv3 = *(const float4*)(brow + k0 + 12);
    }
    __syncthreads();
    #define CVT4(v) (bf16x4){(short)f2bf((v).x), (short)f2bf((v).y), (short)f2bf((v).z), (short)f2bf((v).w)}
    *(bf16x4*)&A_s[r][seg * 16 + 0]  = CVT4(av0);
    *(bf16x4*)&A_s[r][seg * 16 + 4]  = CVT4(av1);
    *(bf16x4*)&A_s[r][seg * 16 + 8]  = CVT4(av2);
    *(bf16x4*)&A_s[r][seg * 16 + 12] = CVT4(av3);
    *(bf16x4*)&B_s[r][seg * 16 + 0]  = CVT4(bv0);
    *(bf16x4*)&B_s[r][seg * 16 + 4]  = CVT4(bv1);
    *(bf16x4*)&B_s[r][seg * 16 + 8]  = CVT4(bv2);
    *(bf16x4*)&B_s[r][seg * 16 + 12] = CVT4(bv3);
    #undef CVT4
    __syncthreads();
    bf16x8 af[4], bf[4];
    #pragma unroll
    for (int i = 0; i < 4; ++i) {
      af[i] = *(const bf16x8*)&A_s[wm * 64 + i * 16 + lm][kg * 8];
      bf[i] = *(const bf16x8*)&B_s[wn * 64 + i * 16 + lm][kg * 8];
    }
    #pragma unroll
    for (int i = 0; i < 4; ++i)
      #pragma unroll
      for (int j = 0; j < 4; ++j)
        acc[i][j] = __builtin_amdgcn_mfma_f32_16x16x32_bf16(af[i], bf[j], acc[i][j], 0, 0, 0);
  }

  #pragma unroll
  for (int i = 0; i < 4; ++i) {
    #pragma unroll
    for (int rr = 0; rr < 4; ++rr) {
      const int mloc = wm * 64 + i * 16 + kg * 4 + rr;
      const float s0 = st_s[mloc][0], s1 = st_s[mloc][1], s2 = st_s[mloc][2];
      float* orow = out + (size_t)(m0 + mloc) * V_ + n0;
      #pragma unroll
      for (int j = 0; j < 4; ++j) {
        const int nloc = wn * 64 + j * 16 + lm;
        if (n0 + nloc < V_) {
          const float corr = 0.1f * (s0 * wm_s[nloc][0] + s1 * wm_s[nloc][1] + s2 * wm_s[nloc][2]);
          orow[nloc] = acc[i][j][rr] + corr;
        }
      }
    }
  }
}

} // namespace

extern "C" void kernel_launch(void* const* d_in, const int* in_sizes, int n_in,
                              void* d_out, int out_size, void* d_ws, size_t ws_size,
                              hipStream_t stream) {
  const float* hidden     = (const float*)d_in[0];
  const float* ttu_state  = (const float*)d_in[1];
  const float* W_imp      = (const float*)d_in[2];
  const float* b_imp      = (const float*)d_in[3];
  const float* W_lm       = (const float*)d_in[4];
  const float* W_mod      = (const float*)d_in[5];
  const float* ttu_params = (const float*)d_in[6];
  float* out = (float*)d_out;

  float* imp    = (float*)d_ws;          // 2048 f32
  float* states = imp + S_ * B_;         // 6144 f32  (32 KB total)

  const size_t need = 32768 + (size_t)M_ * H_ * 2 + (size_t)VP_ * H_ * 2;
  const int grid = ((VP_ / BN) * (M_ / BM));   // 393*16 = 6288

  ttu_impulse_kernel<<<M_, 256, 0, stream>>>(hidden, W_imp, b_imp, imp);
  ttu_scan_kernel<<<1, 64, 0, stream>>>(imp, ttu_state, ttu_params, states,
                                        out + (size_t)B_ * S_ * V_);

  if (ws_size >= need) {
    unsigned short* hid_bf = (unsigned short*)((char*)d_ws + 32768);
    unsigned short* wlm_bf = hid_bf + (size_t)M_ * H_;
    cvt_bf16_kernel<<<2048, 256, 0, stream>>>(hidden, hid_bf,
                                              (long)M_ * H_, (long)M_ * H_);
    cvt_bf16_kernel<<<4096, 256, 0, stream>>>(W_lm, wlm_bf,
                                              (long)V_ * H_, (long)VP_ * H_);
    ttu_gemm_bf16_kernel<<<grid, 256, 0, stream>>>(hid_bf, wlm_bf, states, W_mod, out);
  } else {
    ttu_gemm_kernel<<<grid, 256, 0, stream>>>(hidden, W_lm, states, W_mod, out);
  }
}

// Round 3
// 525.160 us; speedup vs baseline: 1.2021x; 1.1215x over previous
//
#include <hip/hip_runtime.h>
#include <hip/hip_bf16.h>

typedef float  f32x4  __attribute__((ext_vector_type(4)));
typedef short  bf16x8 __attribute__((ext_vector_type(8)));
typedef short  bf16x4 __attribute__((ext_vector_type(4)));

typedef const void __attribute__((address_space(1))) gv_t;
typedef void __attribute__((address_space(3))) sv_t;

namespace {

constexpr int B_ = 2;
constexpr int S_ = 1024;
constexpr int H_ = 1024;
constexpr int V_ = 50257;
constexpr int M_ = B_ * S_;          // 2048
constexpr int VP_ = 50304;           // 393*128, zero-padded W_lm rows
constexpr float DT_ = 0.1f;
constexpr float THRESH_ = 10.0f;

constexpr int BM = 128, BN = 128, BK = 64;
constexpr int NT = H_ / BK;          // 16 K-tiles

__device__ __forceinline__ unsigned short f2bf(float f) {
  union { float f; unsigned u; } x;
  x.f = f;
  x.u += 0x7FFFu + ((x.u >> 16) & 1u);   // RNE (no NaNs in this problem)
  return (unsigned short)(x.u >> 16);
}

// ---------------- Kernel 1: hidden f32 -> bf16, fused with impulse dot
// one block per row m; 256 threads x 4 floats = 1024 = H_
__global__ void cvt_hidden_impulse_kernel(const float* __restrict__ hidden,
                                          const float* __restrict__ W_imp,
                                          const float* __restrict__ b_imp,
                                          unsigned short* __restrict__ hid_bf,
                                          float* __restrict__ imp) {
  const int m = blockIdx.x;
  const int t = threadIdx.x;
  const float4 hv = reinterpret_cast<const float4*>(hidden + (size_t)m * H_)[t];
  const float4 wv = reinterpret_cast<const float4*>(W_imp)[t];   // row 0
  bf16x4 o;
  o[0] = (short)f2bf(hv.x); o[1] = (short)f2bf(hv.y);
  o[2] = (short)f2bf(hv.z); o[3] = (short)f2bf(hv.w);
  *(bf16x4*)(hid_bf + (size_t)m * H_ + t * 4) = o;
  float p = hv.x * wv.x + hv.y * wv.y + hv.z * wv.z + hv.w * wv.w;
  #pragma unroll
  for (int off = 32; off; off >>= 1) p += __shfl_down(p, off);
  __shared__ float partial[4];
  if ((t & 63) == 0) partial[t >> 6] = p;
  __syncthreads();
  if (t == 0) {
    const float v = partial[0] + partial[1] + partial[2] + partial[3] + b_imp[0];
    const int b = m >> 10;
    const int s = m & (S_ - 1);
    imp[s * B_ + b] = v;
  }
}

// ---------------- Kernel 2: serial nonlinear scan
__global__ void ttu_scan_kernel(const float* __restrict__ imp,
                                const float* __restrict__ ttu_state,
                                const float* __restrict__ ttu_params,
                                float* __restrict__ states,
                                float* __restrict__ final_out) {
  __shared__ float imp_s[S_ * B_];
  const int t = threadIdx.x;  // 64
  for (int i = t; i < S_ * B_; i += 64) imp_s[i] = imp[i];
  __syncthreads();
  if (t < B_) {
    const float gamma   = ttu_params[0];
    const float alpha_c = ttu_params[1];
    const float beta_c  = ttu_params[2];
    const float delta   = ttu_params[3];
    const float alpha_d = ttu_params[4];
    const float epsilon = ttu_params[5];
    const float alpha_m = ttu_params[6];
    float c = ttu_state[t * 3 + 0];
    float d = ttu_state[t * 3 + 1];
    float m = ttu_state[t * 3 + 2];
    for (int s = 0; s < S_; ++s) {
      const float ii = imp_s[s * B_ + t];
      const float dc = gamma * ii - alpha_c * c - beta_c * c * d;
      const float dd = delta * c * c - alpha_d * d;
      const float dm = epsilon * d - alpha_m * m;
      c = c + DT_ * dc;
      float nd = d + DT_ * dd;
      m = m + DT_ * dm;
      nd = (fabsf(nd) > THRESH_ ? 0.5f : 1.0f) * nd;
      d = nd;
      float* st = states + (size_t)(s * B_ + t) * 3;
      st[0] = c; st[1] = d; st[2] = m;
    }
    final_out[t * 3 + 0] = c;
    final_out[t * 3 + 1] = d;
    final_out[t * 3 + 2] = m;
  }
}

// ---------------- Kernel 2.5: W_lm f32 -> bf16 (zero-fill pad rows)
__global__ void cvt_bf16_kernel(const float* __restrict__ src,
                                unsigned short* __restrict__ dst,
                                long n_src, long n_dst) {
  const long stride = (long)gridDim.x * blockDim.x * 8;
  for (long i = ((long)blockIdx.x * blockDim.x + threadIdx.x) * 8; i < n_dst; i += stride) {
    bf16x8 v;
    if (i < n_src) {     // n_src is a multiple of 8; vectors never straddle
      const float4 a = *(const float4*)(src + i);
      const float4 b = *(const float4*)(src + i + 4);
      v[0] = (short)f2bf(a.x); v[1] = (short)f2bf(a.y);
      v[2] = (short)f2bf(a.z); v[3] = (short)f2bf(a.w);
      v[4] = (short)f2bf(b.x); v[5] = (short)f2bf(b.y);
      v[6] = (short)f2bf(b.z); v[7] = (short)f2bf(b.w);
    } else {
      v = (bf16x8){0, 0, 0, 0, 0, 0, 0, 0};
    }
    *(bf16x8*)(dst + i) = v;
  }
}

// ---------------- Kernel 3: bf16 GEMM, T3-minimum 2-phase double-buffer
// LDS chunk swizzle: row's 16B chunk c holds global chunk c ^ (row&7);
// achieved by pre-swizzling the per-lane GLOBAL address (linear LDS dest,
// rule #21), ds_read applies the same XOR. BANK_CONFLICT==0 verified R2.
// Loop (T3 minimum-2-phase recipe): prefetch kt+1 -> ds_read/MFMA kt ->
// one vmcnt(0)+barrier per tile (inside __syncthreads), swap buffers.
__global__ __launch_bounds__(256) void ttu_gemm_bf16_db_kernel(
    const unsigned short* __restrict__ Ab,   // hidden bf16 [M_][H_]
    const unsigned short* __restrict__ Bb,   // W_lm bf16 [VP_][H_]
    const float* __restrict__ states,
    const float* __restrict__ Wmod,
    float* __restrict__ out)
{
  __shared__ unsigned short AB_s[2][2][BM * BK];   // [buf][A|B][...], 64 KiB
  __shared__ float st_s[BM][3];
  __shared__ float wm_s[BN][3];

  const int t = threadIdx.x;
  // T1: XCD-chunked swizzle; grid = 6288 % 8 == 0 -> bijective simple form
  const int cpx = gridDim.x >> 3;
  const int bid = (blockIdx.x & 7) * cpx + (blockIdx.x >> 3);
  const int mb = bid & 15;             // M fastest: 16 consecutive blocks share B-panel
  const int nb = bid >> 4;
  const int m0 = mb * BM;
  const int n0 = nb * BN;

  // epilogue operands
  if (t < BM) {
    const int m = m0 + t;
    const int b = m >> 10;
    const int s = m & (S_ - 1);
    const float* st = states + (size_t)(s * B_ + b) * 3;
    st_s[t][0] = st[0]; st_s[t][1] = st[1]; st_s[t][2] = st[2];
  } else {
    const int tt = t - BM;
    const int n = n0 + tt;
    const bool ok = n < V_;
    wm_s[tt][0] = ok ? Wmod[n * 3 + 0] : 0.f;
    wm_s[tt][1] = ok ? Wmod[n * 3 + 1] : 0.f;
    wm_s[tt][2] = ok ? Wmod[n * 3 + 2] : 0.f;
  }

  const int lane = t & 63;
  const int wid  = t >> 6;             // 4 waves
  const int lr   = lane >> 3;          // staging sub-row 0..7
  const int ch   = lane & 7;           // staging 16B chunk 0..7
  const int wm   = wid >> 1;           // 2x2 wave grid
  const int wn   = wid & 1;
  const int lm   = lane & 15;
  const int kg   = lane >> 4;

  const unsigned short* Abase = Ab + (size_t)m0 * H_;
  const unsigned short* Bbase = Bb + (size_t)n0 * H_;

  // per-lane swizzled global addresses for the 4 staging instrs (per matrix)
  const int r0 = wid * 32;             // wave's first staged row
  auto STAGE = [&](unsigned short* As, unsigned short* Bs, int kt) {
    const int k0 = kt * BK;
    #pragma unroll
    for (int ins = 0; ins < 4; ++ins) {
      const int lrow = r0 + ins * 8 + lr;
      const int sch  = ch ^ (lrow & 7);
      __builtin_amdgcn_global_load_lds(
          (gv_t*)(Abase + (size_t)lrow * H_ + k0 + sch * 8),
          (sv_t*)(As + (r0 + ins * 8) * BK), 16, 0, 0);
    }
    #pragma unroll
    for (int ins = 0; ins < 4; ++ins) {
      const int lrow = r0 + ins * 8 + lr;
      const int sch  = ch ^ (lrow & 7);
      __builtin_amdgcn_global_load_lds(
          (gv_t*)(Bbase + (size_t)lrow * H_ + k0 + sch * 8),
          (sv_t*)(Bs + (r0 + ins * 8) * BK), 16, 0, 0);
    }
  };

  f32x4 acc[4][4];
  #pragma unroll
  for (int i = 0; i < 4; ++i)
    #pragma unroll
    for (int j = 0; j < 4; ++j)
      acc[i][j] = (f32x4){0.f, 0.f, 0.f, 0.f};

  unsigned short* Ac = &AB_s[0][0][0];   // compute buffers
  unsigned short* Bc = &AB_s[0][1][0];
  unsigned short* An = &AB_s[1][0][0];   // prefetch buffers
  unsigned short* Bn = &AB_s[1][1][0];

  STAGE(Ac, Bc, 0);
  __syncthreads();                       // vmcnt(0) drain: tile 0 visible

  for (int kt = 0; kt < NT; ++kt) {
    if (kt + 1 < NT) STAGE(An, Bn, kt + 1);   // issue next-tile loads FIRST

    bf16x8 af[4][2], bfr[4][2];
    #pragma unroll
    for (int i = 0; i < 4; ++i) {
      const int arow = wm * 64 + i * 16 + lm;
      const int brow = wn * 64 + i * 16 + lm;
      #pragma unroll
      for (int ks = 0; ks < 2; ++ks) {
        af[i][ks]  = *(const bf16x8*)&Ac[arow * BK + (((ks * 4 + kg) ^ (arow & 7)) << 3)];
        bfr[i][ks] = *(const bf16x8*)&Bc[brow * BK + (((ks * 4 + kg) ^ (brow & 7)) << 3)];
      }
    }
    #pragma unroll
    for (int ks = 0; ks < 2; ++ks)
      #pragma unroll
      for (int i = 0; i < 4; ++i)
        #pragma unroll
        for (int j = 0; j < 4; ++j)
          acc[i][j] = __builtin_amdgcn_mfma_f32_16x16x32_bf16(af[i][ks], bfr[j][ks], acc[i][j], 0, 0, 0);

    __syncthreads();   // single vmcnt(0)+barrier per tile: prefetch landed,
                       // all reads of compute buf done -> safe to swap
    unsigned short* tp;
    tp = Ac; Ac = An; An = tp;
    tp = Bc; Bc = Bn; Bn = tp;
  }

  // Epilogue: += 0.1 * states . W_mod^T; row-major store order
  #pragma unroll
  for (int i = 0; i < 4; ++i) {
    #pragma unroll
    for (int rr = 0; rr < 4; ++rr) {
      const int mloc = wm * 64 + i * 16 + kg * 4 + rr;
      const float s0 = st_s[mloc][0], s1 = st_s[mloc][1], s2 = st_s[mloc][2];
      float* orow = out + (size_t)(m0 + mloc) * V_ + n0;
      #pragma unroll
      for (int j = 0; j < 4; ++j) {
        const int nloc = wn * 64 + j * 16 + lm;
        if (n0 + nloc < V_) {
          const float corr = 0.1f * (s0 * wm_s[nloc][0] + s1 * wm_s[nloc][1] + s2 * wm_s[nloc][2]);
          orow[nloc] = acc[i][j][rr] + corr;
        }
      }
    }
  }
}

// ---------------- Fallback (ws too small): f32 reg-staged GEMM (R1)
__global__ __launch_bounds__(256) void ttu_gemm_kernel(
    const float* __restrict__ Ag, const float* __restrict__ Bg,
    const float* __restrict__ states, const float* __restrict__ Wmod,
    float* __restrict__ out)
{
  __shared__ unsigned short A_s[BM][40];
  __shared__ unsigned short B_s[BM][40];
  __shared__ float st_s[BM][3];
  __shared__ float wm_s[BM][3];

  const int t   = threadIdx.x;
  const int bid = blockIdx.x;
  const int mb  = bid & 15;
  const int nb  = bid >> 4;
  const int m0  = mb * BM;
  const int n0  = nb * BM;

  if (t < BM) {
    const int m = m0 + t;
    const int b = m >> 10;
    const int s = m & (S_ - 1);
    const float* st = states + (size_t)(s * B_ + b) * 3;
    st_s[t][0] = st[0]; st_s[t][1] = st[1]; st_s[t][2] = st[2];
  } else {
    const int tt = t - BM;
    const int n  = n0 + tt;
    const bool ok = n < V_;
    wm_s[tt][0] = ok ? Wmod[n * 3 + 0] : 0.f;
    wm_s[tt][1] = ok ? Wmod[n * 3 + 1] : 0.f;
    wm_s[tt][2] = ok ? Wmod[n * 3 + 2] : 0.f;
  }

  const int r   = t >> 1;
  const int seg = t & 1;
  const float* arow = Ag + (size_t)(m0 + r) * H_ + seg * 16;
  const int  vrow = n0 + r;
  const bool bok  = vrow < V_;
  const float* brow = Bg + (size_t)(bok ? vrow : 0) * H_ + seg * 16;

  const int lane = t & 63;
  const int wid  = t >> 6;
  const int wm   = wid >> 1;
  const int wn   = wid & 1;
  const int lm   = lane & 15;
  const int kg   = lane >> 4;

  f32x4 acc[4][4];
  #pragma unroll
  for (int i = 0; i < 4; ++i)
    #pragma unroll
    for (int j = 0; j < 4; ++j)
      acc[i][j] = (f32x4){0.f, 0.f, 0.f, 0.f};

  for (int kt = 0; kt < H_ / 32; ++kt) {
    const int k0 = kt * 32;
    const float4 av0 = *(const float4*)(arow + k0 + 0);
    const float4 av1 = *(const float4*)(arow + k0 + 4);
    const float4 av2 = *(const float4*)(arow + k0 + 8);
    const float4 av3 = *(const float4*)(arow + k0 + 12);
    float4 bv0 = {0,0,0,0}, bv1 = {0,0,0,0}, bv2 = {0,0,0,0}, bv3 = {0,0,0,0};
    if (bok) {
      bv0 = *(const float4*)(brow + k0 + 0);
      bv1 = *(const float4*)(brow + k0 + 4);
      bv2 = *(const float4*)(brow + k0 + 8);
      bv3 = *(const float4*)(brow + k0 + 12);
    }
    __syncthreads();
    #define CVT4(v) (bf16x4){(short)f2bf((v).x), (short)f2bf((v).y), (short)f2bf((v).z), (short)f2bf((v).w)}
    *(bf16x4*)&A_s[r][seg * 16 + 0]  = CVT4(av0);
    *(bf16x4*)&A_s[r][seg * 16 + 4]  = CVT4(av1);
    *(bf16x4*)&A_s[r][seg * 16 + 8]  = CVT4(av2);
    *(bf16x4*)&A_s[r][seg * 16 + 12] = CVT4(av3);
    *(bf16x4*)&B_s[r][seg * 16 + 0]  = CVT4(bv0);
    *(bf16x4*)&B_s[r][seg * 16 + 4]  = CVT4(bv1);
    *(bf16x4*)&B_s[r][seg * 16 + 8]  = CVT4(bv2);
    *(bf16x4*)&B_s[r][seg * 16 + 12] = CVT4(bv3);
    #undef CVT4
    __syncthreads();
    bf16x8 af[4], bf[4];
    #pragma unroll
    for (int i = 0; i < 4; ++i) {
      af[i] = *(const bf16x8*)&A_s[wm * 64 + i * 16 + lm][kg * 8];
      bf[i] = *(const bf16x8*)&B_s[wn * 64 + i * 16 + lm][kg * 8];
    }
    #pragma unroll
    for (int i = 0; i < 4; ++i)
      #pragma unroll
      for (int j = 0; j < 4; ++j)
        acc[i][j] = __builtin_amdgcn_mfma_f32_16x16x32_bf16(af[i], bf[j], acc[i][j], 0, 0, 0);
  }

  #pragma unroll
  for (int i = 0; i < 4; ++i) {
    #pragma unroll
    for (int rr = 0; rr < 4; ++rr) {
      const int mloc = wm * 64 + i * 16 + kg * 4 + rr;
      const float s0 = st_s[mloc][0], s1 = st_s[mloc][1], s2 = st_s[mloc][2];
      float* orow = out + (size_t)(m0 + mloc) * V_ + n0;
      #pragma unroll
      for (int j = 0; j < 4; ++j) {
        const int nloc = wn * 64 + j * 16 + lm;
        if (n0 + nloc < V_) {
          const float corr = 0.1f * (s0 * wm_s[nloc][0] + s1 * wm_s[nloc][1] + s2 * wm_s[nloc][2]);
          orow[nloc] = acc[i][j][rr] + corr;
        }
      }
    }
  }
}

} // namespace

extern "C" void kernel_launch(void* const* d_in, const int* in_sizes, int n_in,
                              void* d_out, int out_size, void* d_ws, size_t ws_size,
                              hipStream_t stream) {
  const float* hidden     = (const float*)d_in[0];
  const float* ttu_state  = (const float*)d_in[1];
  const float* W_imp      = (const float*)d_in[2];
  const float* b_imp      = (const float*)d_in[3];
  const float* W_lm       = (const float*)d_in[4];
  const float* W_mod      = (const float*)d_in[5];
  const float* ttu_params = (const float*)d_in[6];
  float* out = (float*)d_out;

  float* imp    = (float*)d_ws;          // 2048 f32
  float* states = imp + S_ * B_;         // 6144 f32  (32 KB total)

  const size_t need = 32768 + (size_t)M_ * H_ * 2 + (size_t)VP_ * H_ * 2;
  const int grid = (VP_ / BN) * (M_ / BM);   // 393*16 = 6288

  if (ws_size >= need) {
    unsigned short* hid_bf = (unsigned short*)((char*)d_ws + 32768);
    unsigned short* wlm_bf = hid_bf + (size_t)M_ * H_;
    cvt_hidden_impulse_kernel<<<M_, 256, 0, stream>>>(hidden, W_imp, b_imp, hid_bf, imp);
    ttu_scan_kernel<<<1, 64, 0, stream>>>(imp, ttu_state, ttu_params, states,
                                          out + (size_t)B_ * S_ * V_);
    cvt_bf16_kernel<<<4096, 256, 0, stream>>>(W_lm, wlm_bf,
                                              (long)V_ * H_, (long)VP_ * H_);
    ttu_gemm_bf16_db_kernel<<<grid, 256, 0, stream>>>(hid_bf, wlm_bf, states, W_mod, out);
  } else {
    // fallback: impulse via fused kernel needs hid_bf; do minimal path
    cvt_hidden_impulse_kernel<<<M_, 256, 0, stream>>>(hidden, W_imp, b_imp,
                                                      (unsigned short*)d_ws /*unused scratch*/, imp);
    ttu_scan_kernel<<<1, 64, 0, stream>>>(imp, ttu_state, ttu_params, states,
                                          out + (size_t)B_ * S_ * V_);
    ttu_gemm_kernel<<<grid, 256, 0, stream>>>(hidden, W_lm, states, W_mod, out);
  }
}